// Round 6
// baseline (293.995 us; speedup 1.0000x reference)
//
#include <hip/hip_runtime.h>
#include <stdint.h>

#define B_ 4
#define S_ 1024
#define D_ 2048
#define H_ 16
#define HD 128
#define E_ 6144

typedef short bf16x8 __attribute__((ext_vector_type(8)));
typedef float f32x4 __attribute__((ext_vector_type(4)));

__device__ __forceinline__ unsigned short f2bf(float f) {
  union { float f; unsigned u; } x; x.f = f;
  unsigned r = x.u + 0x7fffu + ((x.u >> 16) & 1u);
  return (unsigned short)(r >> 16);
}

__device__ __forceinline__ void gl_lds16(const void* g, void* l) {
  __builtin_amdgcn_global_load_lds(
      (const __attribute__((address_space(1))) void*)g,
      (__attribute__((address_space(3))) void*)l, 16, 0, 0);
}

// DPP cross-lane within the 16-lane row: single-cycle VALU, no LDS pipe.
template <int C>
__device__ __forceinline__ float dppf(float x) {
  union { float f; int i; } u; u.f = x;
  u.i = __builtin_amdgcn_update_dpp(u.i, u.i, C, 0xF, 0xF, true);
  return u.f;
}
__device__ __forceinline__ float red_max16(float v) {
  v = fmaxf(v, dppf<0xB1>(v));   // quad_perm [1,0,3,2]  (xor 1)
  v = fmaxf(v, dppf<0x4E>(v));   // quad_perm [2,3,0,1]  (xor 2)
  v = fmaxf(v, dppf<0x124>(v));  // row_ror:4
  v = fmaxf(v, dppf<0x128>(v));  // row_ror:8
  return v;
}
__device__ __forceinline__ float red_sum16(float v) {
  v += dppf<0xB1>(v);
  v += dppf<0x4E>(v);
  v += dppf<0x124>(v);
  v += dppf<0x128>(v);
  return v;
}

// ---- fp32 -> bf16 fragment-tiled cast via LDS repack ----
__global__ __launch_bounds__(256) void cvt_repack(const float* __restrict__ src,
                                                  short* __restrict__ dst) {
  __shared__ __align__(16) short L[128 * 40];
  const int tid = threadIdx.x;
  const int kt = blockIdx.x & 63, mt = blockIdx.x >> 6;
  {
    int row = tid >> 1, half = tid & 1;
    const float* p = src + (size_t)(mt * 128 + row) * D_ + kt * 32 + half * 16;
    float4 v0 = *(const float4*)(p);
    float4 v1 = *(const float4*)(p + 4);
    float4 v2 = *(const float4*)(p + 8);
    float4 v3 = *(const float4*)(p + 12);
    union { short s[16]; int4 v[2]; } u;
    u.s[0] = (short)f2bf(v0.x);  u.s[1] = (short)f2bf(v0.y);
    u.s[2] = (short)f2bf(v0.z);  u.s[3] = (short)f2bf(v0.w);
    u.s[4] = (short)f2bf(v1.x);  u.s[5] = (short)f2bf(v1.y);
    u.s[6] = (short)f2bf(v1.z);  u.s[7] = (short)f2bf(v1.w);
    u.s[8] = (short)f2bf(v2.x);  u.s[9] = (short)f2bf(v2.y);
    u.s[10] = (short)f2bf(v2.z); u.s[11] = (short)f2bf(v2.w);
    u.s[12] = (short)f2bf(v3.x); u.s[13] = (short)f2bf(v3.y);
    u.s[14] = (short)f2bf(v3.z); u.s[15] = (short)f2bf(v3.w);
    int4* lp = (int4*)(L + row * 40 + half * 16);
    lp[0] = u.v[0];
    lp[1] = u.v[1];
  }
  __syncthreads();
  short* out = dst + (((size_t)(mt * 64 + kt)) << 12);
#pragma unroll
  for (int i = 0; i < 2; i++) {
    int ch = i * 256 + tid;
    int cc = ch & 15, qq = (ch >> 4) & 3, rt = ch >> 6;
    int4 v = *(const int4*)(L + (rt * 16 + cc) * 40 + qq * 8);
    *(int4*)(out + ch * 8) = v;
  }
}

// ---------------- RoPE cos/sin table ----------------
__global__ __launch_bounds__(256) void rope_tbl(float2* __restrict__ t) {
  int idx = blockIdx.x * 256 + threadIdx.x;  // 65536
  int s = idx >> 6, j = idx & 63;
  float inv = exp2f(-0.20762050593045953f * (float)j);
  float a = (float)s * inv;
  t[idx] = make_float2(cosf(a), sinf(a));
}

// ---------------- QKV GEMM + bias + RoPE + fragment-order scatter ----------
__global__ __launch_bounds__(256) void qkv_gemm(
    const short* __restrict__ Xt, const short* __restrict__ Wt,
    const float* __restrict__ bq, const float2* __restrict__ rope,
    short* __restrict__ Qg, short* __restrict__ Kg, short* __restrict__ Vg) {
  __shared__ __align__(16) short As[4096];
  __shared__ __align__(16) short Bs[4096];

  const int tid = threadIdx.x;
  const int w = tid >> 6, lane = tid & 63;
  const int q = lane >> 4, c = lane & 15;
  const int wy = w >> 1, wx = w & 1;
  const int bn = blockIdx.x, bm = blockIdx.y;

  const short* Abase = Xt + (size_t)bm * 64 * 4096;
  const short* Bbase = Wt + (size_t)bn * 64 * 4096;

  f32x4 acc[4][4];
#pragma unroll
  for (int i = 0; i < 4; i++)
#pragma unroll
    for (int jl = 0; jl < 4; jl++) acc[i][jl] = (f32x4){0.f, 0.f, 0.f, 0.f};

  for (int kt = 0; kt < 64; kt++) {
    const short* Ak = Abase + (size_t)kt * 4096;
    const short* Bk = Bbase + (size_t)kt * 4096;
#pragma unroll
    for (int i = 0; i < 2; i++) {
      int ch = i * 256 + tid;
      gl_lds16(Ak + ch * 8, As + ch * 8);
      gl_lds16(Bk + ch * 8, Bs + ch * 8);
    }
    __syncthreads();
    bf16x8 a[4], b[4];
#pragma unroll
    for (int i = 0; i < 4; i++)
      a[i] = *(const bf16x8*)(As + (wy * 4 + i) * 512 + lane * 8);
#pragma unroll
    for (int jl = 0; jl < 4; jl++) {
      int ct = 2 * wx + (jl & 1) + ((jl >> 1) << 2);
      b[jl] = *(const bf16x8*)(Bs + ct * 512 + lane * 8);
    }
#pragma unroll
    for (int i = 0; i < 4; i++)
#pragma unroll
      for (int jl = 0; jl < 4; jl++)
        acc[i][jl] = __builtin_amdgcn_mfma_f32_16x16x32_bf16(a[i], b[jl], acc[i][jl], 0, 0, 0);
    __syncthreads();
  }

  const int head = bn / 3, typ = bn - head * 3;
  const int b = bm >> 3;
  const int bh = b * H_ + head;
  const int s0 = (bm & 7) << 7;

  int ctl[4];
  float bias[4];
#pragma unroll
  for (int jl = 0; jl < 4; jl++) {
    ctl[jl] = 2 * wx + (jl & 1) + ((jl >> 1) << 2);
    bias[jl] = bq[bn * 128 + ctl[jl] * 16 + c];
  }
#pragma unroll
  for (int i = 0; i < 4; i++)
#pragma unroll
    for (int jl = 0; jl < 4; jl++)
#pragma unroll
      for (int r = 0; r < 4; r++) acc[i][jl][r] += bias[jl];

  if (typ < 2) {
#pragma unroll
    for (int i = 0; i < 4; i++)
#pragma unroll
      for (int r = 0; r < 4; r++) {
        int s = s0 + wy * 64 + i * 16 + q * 4 + r;
#pragma unroll
        for (int jl = 0; jl < 2; jl++) {
          float2 cs = rope[s * 64 + ctl[jl] * 16 + c];
          float x1 = acc[i][jl][r], x2 = acc[i][jl + 2][r];
          acc[i][jl][r] = x1 * cs.x - x2 * cs.y;
          acc[i][jl + 2][r] = x2 * cs.x + x1 * cs.y;
        }
      }
    if (typ == 0) {
      short* dst = Qg + (size_t)bh * S_ * HD;
#pragma unroll
      for (int i = 0; i < 4; i++)
#pragma unroll
        for (int r = 0; r < 4; r++) {
          int s = s0 + wy * 64 + i * 16 + q * 4 + r;
          short* row = dst + (size_t)s * HD;
#pragma unroll
          for (int jl = 0; jl < 4; jl++)
            row[ctl[jl] * 16 + c] = (short)f2bf(acc[i][jl][r] * 0.08838834764831845f);
        }
    } else {
      short* dst = Kg + (size_t)bh * 16 * 8192 + (size_t)((s0 >> 6) + wy) * 8192;
#pragma unroll
      for (int i = 0; i < 4; i++)
#pragma unroll
        for (int jl = 0; jl < 4; jl++) {
          int ks = ctl[jl] >> 1;
          int qqf = ((ctl[jl] & 1) << 1) + (c >> 3);
          short* p = dst + (ks * 4 + i) * 512 + qqf * 128 + (c & 7);
#pragma unroll
          for (int r = 0; r < 4; r++)
            p[(q * 4 + r) * 8] = (short)f2bf(acc[i][jl][r]);
        }
    }
  } else {
    short* dst = Vg + (size_t)bh * 16 * 8192 + (size_t)((s0 >> 6) + wy) * 8192;
#pragma unroll
    for (int i = 0; i < 4; i++)
#pragma unroll
      for (int jl = 0; jl < 4; jl++)
#pragma unroll
        for (int r = 0; r < 4; r++) {
          int sl = q * 4 + r;
          int qqf = ((i & 1) << 1) + (sl >> 3);
          dst[((i >> 1) * 8 + ctl[jl]) * 512 + qqf * 128 + c * 8 + (sl & 7)] =
              (short)f2bf(acc[i][jl][r]);
        }
  }
}

// ---------------- causal flash attention ----------------
// 512-thread blocks, q-tile 128 (8 waves x 16 q-rows), KT=64.
// Paired q-tiles (p, 7-p): every block does exactly 18 tile-iterations.
// K double-buffered; manual s_waitcnt vmcnt(N) + raw s_barrier pipelining.
__global__ __launch_bounds__(512) void flash_attn(
    const short* __restrict__ Qg, const short* __restrict__ Kg,
    const short* __restrict__ Vg, float* __restrict__ out) {
  __shared__ __align__(16) short Kb[2][8192];  // 32 KB
  __shared__ __align__(16) short Vb[8192];     // 16 KB
  __shared__ __align__(16) short Ps[8192];     // 16 KB, wave-private 2 KB regions

  const int tid = threadIdx.x;
  const int w = tid >> 6, lane = tid & 63;
  const int q = lane >> 4, c = lane & 15;
  const int bh = blockIdx.x, pp = blockIdx.y;  // XCD = bh%8 -> balanced
  const int b = bh >> 4, h = bh & 15;

  const short* Qh = Qg + (size_t)bh * S_ * HD;
  const short* Kh = Kg + (size_t)bh * 16 * 8192;
  const short* Vh = Vg + (size_t)bh * 16 * 8192;

#pragma unroll
  for (int ph = 0; ph < 2; ph++) {
    const int qt = ph ? 7 - pp : pp;
    const int q0 = qt * 128;
    const int n = 2 * qt + 2;  // 64-wide k-tiles covering k < q0+128

    bf16x8 aq[4];  // wave w owns q-rows q0 + w*16 + [0,16)
#pragma unroll
    for (int ks = 0; ks < 4; ks++)
      aq[ks] = *(const bf16x8*)(Qh + (size_t)(q0 + w * 16 + c) * HD + ks * 32 + q * 8);

    f32x4 o[8];
    float m_[4], l_[4];
#pragma unroll
    for (int tj = 0; tj < 8; tj++) o[tj] = (f32x4){0.f, 0.f, 0.f, 0.f};
#pragma unroll
    for (int r = 0; r < 4; r++) { m_[r] = -1e30f; l_[r] = 0.f; }

    // pre-stage K0 (2 instr/thread) then V0 (2 instr/thread)
#pragma unroll
    for (int i = 0; i < 2; i++) {
      int ch = i * 512 + tid;
      gl_lds16(Kh + ch * 8, &Kb[0][ch * 8]);
    }
#pragma unroll
    for (int i = 0; i < 2; i++) {
      int ch = i * 512 + tid;
      gl_lds16(Vh + ch * 8, Vb + ch * 8);
    }

    for (int it = 0; it < n; it++) {
      const int cur = it & 1;
      // wait K(it); newest 2 (V(it)) stay in flight
      asm volatile("s_waitcnt vmcnt(2)" ::: "memory");
      __builtin_amdgcn_s_barrier();  // B1: K(it) visible

      f32x4 s[4];
#pragma unroll
      for (int tj = 0; tj < 4; tj++) s[tj] = (f32x4){0.f, 0.f, 0.f, 0.f};
#pragma unroll
      for (int ks = 0; ks < 4; ks++)
#pragma unroll
        for (int tj = 0; tj < 4; tj++) {
          bf16x8 bk = *(const bf16x8*)(&Kb[cur][(ks * 4 + tj) * 512 + lane * 8]);
          s[tj] = __builtin_amdgcn_mfma_f32_16x16x32_bf16(aq[ks], bk, s[tj], 0, 0, 0);
        }

      // prefetch K(it+1); last reader of Kb[cur^1] finished before B2(it-1)
      if (it + 1 < n) {
#pragma unroll
        for (int i = 0; i < 2; i++) {
          int ch = i * 512 + tid;
          gl_lds16(Kh + (size_t)(it + 1) * 8192 + ch * 8, &Kb[cur ^ 1][ch * 8]);
        }
      }

      if (it >= 2 * qt) {  // diagonal-overlapping tiles: causal mask
#pragma unroll
        for (int tj = 0; tj < 4; tj++) {
          int kg = it * 64 + tj * 16 + c;
#pragma unroll
          for (int r = 0; r < 4; r++) {
            int qg = q0 + w * 16 + q * 4 + r;
            if (kg > qg) s[tj][r] = -1e30f;
          }
        }
      }

      // online softmax (DPP reductions within the 16-lane col group)
#pragma unroll
      for (int r = 0; r < 4; r++) {
        float mx = fmaxf(fmaxf(s[0][r], s[1][r]), fmaxf(s[2][r], s[3][r]));
        mx = red_max16(mx);
        float mn = fmaxf(m_[r], mx);
        float alpha = __expf(m_[r] - mn);
        m_[r] = mn;
        float rs = 0.f;
#pragma unroll
        for (int tj = 0; tj < 4; tj++) {
          float e = __expf(s[tj][r] - mn);
          s[tj][r] = e;
          rs += e;
        }
        rs = red_sum16(rs);
        l_[r] = l_[r] * alpha + rs;
#pragma unroll
        for (int tjd = 0; tjd < 8; tjd++) o[tjd][r] *= alpha;
      }

      // wait V(it): only K(it+1) prefetch (2, newer) may remain
      if (it + 1 < n)
        asm volatile("s_waitcnt vmcnt(2)" ::: "memory");
      else
        asm volatile("s_waitcnt vmcnt(0)" ::: "memory");
      __builtin_amdgcn_s_barrier();  // B2: V(it) visible

      // P: C-layout -> wave-private A-layout region (2 KB per wave)
#pragma unroll
      for (int tj = 0; tj < 4; tj++) {
        int base = w * 1024 + (tj >> 1) * 512 + (((tj & 1) << 1) + (c >> 3)) * 128 + (c & 7);
#pragma unroll
        for (int r = 0; r < 4; r++)
          Ps[base + (q * 4 + r) * 8] = (short)f2bf(s[tj][r]);
      }

#pragma unroll
      for (int ks2 = 0; ks2 < 2; ks2++) {
        bf16x8 ap = *(const bf16x8*)(Ps + w * 1024 + ks2 * 512 + lane * 8);
#pragma unroll
        for (int tjd = 0; tjd < 8; tjd++) {
          bf16x8 bv = *(const bf16x8*)(Vb + (ks2 * 8 + tjd) * 512 + lane * 8);
          o[tjd] = __builtin_amdgcn_mfma_f32_16x16x32_bf16(ap, bv, o[tjd], 0, 0, 0);
        }
      }
      __builtin_amdgcn_s_barrier();  // B3: all waves done reading Vb

      // stage V(it+1); drains at B2(it+1), overlapped by QK+softmax
      if (it + 1 < n) {
#pragma unroll
        for (int i = 0; i < 2; i++) {
          int ch = i * 512 + tid;
          gl_lds16(Vh + (size_t)(it + 1) * 8192 + ch * 8, Vb + ch * 8);
        }
      }
    }

#pragma unroll
    for (int r = 0; r < 4; r++) {
      float inv = 1.0f / l_[r];
      int sg = q0 + w * 16 + q * 4 + r;
      float* dst = out + (size_t)(b * S_ + sg) * D_ + h * HD;
#pragma unroll
      for (int tjd = 0; tjd < 8; tjd++) dst[tjd * 16 + c] = o[tjd][r] * inv;
    }
    // phase ends with zero outstanding staging loads (last iter stages nothing);
    // phase-1 B1's vmcnt(2) also drains these output stores (correct, cheap).
  }
}

extern "C" void kernel_launch(void* const* d_in, const int* in_sizes, int n_in,
                              void* d_out, int out_size, void* d_ws, size_t ws_size,
                              hipStream_t stream) {
  (void)in_sizes; (void)n_in; (void)out_size; (void)ws_size;
  const float* hs = (const float*)d_in[0];
  const float* wq = (const float*)d_in[1];
  const float* bq = (const float*)d_in[2];
  char* ws = (char*)d_ws;
  short* Xt = (short*)(ws);
  short* Wt = (short*)(ws + 16777216);
  short* Qg = (short*)(ws + 41943040);
  short* Kg = (short*)(ws + 58720256);
  short* Vg = (short*)(ws + 75497472);
  float2* tbl = (float2*)(ws + 92274688);

  hipLaunchKernelGGL(cvt_repack, dim3(32 * 64), dim3(256), 0, stream, hs, Xt);
  hipLaunchKernelGGL(cvt_repack, dim3(48 * 64), dim3(256), 0, stream, wq, Wt);
  hipLaunchKernelGGL(rope_tbl, dim3(256), dim3(256), 0, stream, tbl);
  hipLaunchKernelGGL(qkv_gemm, dim3(48, 32), dim3(256), 0, stream, Xt, Wt, bq, tbl, Qg, Kg, Vg);
  hipLaunchKernelGGL(flash_attn, dim3(64, 4), dim3(512), 0, stream, Qg, Kg, Vg, (float*)d_out);
}

// Round 7
// 289.103 us; speedup vs baseline: 1.0169x; 1.0169x over previous
//
#include <hip/hip_runtime.h>
#include <stdint.h>

#define B_ 4
#define S_ 1024
#define D_ 2048
#define H_ 16
#define HD 128
#define E_ 6144

typedef short bf16x8 __attribute__((ext_vector_type(8)));
typedef float f32x4 __attribute__((ext_vector_type(4)));

__device__ __forceinline__ unsigned short f2bf(float f) {
  union { float f; unsigned u; } x; x.f = f;
  unsigned r = x.u + 0x7fffu + ((x.u >> 16) & 1u);
  return (unsigned short)(r >> 16);
}

__device__ __forceinline__ void gl_lds16(const void* g, void* l) {
  __builtin_amdgcn_global_load_lds(
      (const __attribute__((address_space(1))) void*)g,
      (__attribute__((address_space(3))) void*)l, 16, 0, 0);
}

// DPP cross-lane within the 16-lane row: single-cycle VALU, no LDS pipe.
template <int C>
__device__ __forceinline__ float dppf(float x) {
  union { float f; int i; } u; u.f = x;
  u.i = __builtin_amdgcn_update_dpp(u.i, u.i, C, 0xF, 0xF, true);
  return u.f;
}
__device__ __forceinline__ float red_max16(float v) {
  v = fmaxf(v, dppf<0xB1>(v));   // quad_perm [1,0,3,2]  (xor 1)
  v = fmaxf(v, dppf<0x4E>(v));   // quad_perm [2,3,0,1]  (xor 2)
  v = fmaxf(v, dppf<0x124>(v));  // row_ror:4
  v = fmaxf(v, dppf<0x128>(v));  // row_ror:8
  return v;
}
__device__ __forceinline__ float red_sum16(float v) {
  v += dppf<0xB1>(v);
  v += dppf<0x4E>(v);
  v += dppf<0x124>(v);
  v += dppf<0x128>(v);
  return v;
}

// ---- fused preprocessing: X cvt (2048 blk) | W cvt (3072 blk) | rope (256 blk)
__global__ __launch_bounds__(256) void prep(const float* __restrict__ X,
                                            short* __restrict__ Xt,
                                            const float* __restrict__ W,
                                            short* __restrict__ Wt,
                                            float2* __restrict__ tbl) {
  int blk = blockIdx.x;
  const int tid = threadIdx.x;

  if (blk >= 5120) {  // rope table: [s][j], j in [0,64)
    int idx = (blk - 5120) * 256 + tid;  // 65536
    int s = idx >> 6, j = idx & 63;
    float inv = exp2f(-0.20762050593045953f * (float)j);
    float a = (float)s * inv;
    tbl[idx] = make_float2(cosf(a), sinf(a));
    return;
  }

  const float* src;
  short* dst;
  if (blk < 2048) {
    src = X; dst = Xt;
  } else {
    blk -= 2048; src = W; dst = Wt;
  }

  __shared__ __align__(16) short L[128 * 40];
  const int kt = blk & 63, mt = blk >> 6;
  {
    int row = tid >> 1, half = tid & 1;
    const float* p = src + (size_t)(mt * 128 + row) * D_ + kt * 32 + half * 16;
    float4 v0 = *(const float4*)(p);
    float4 v1 = *(const float4*)(p + 4);
    float4 v2 = *(const float4*)(p + 8);
    float4 v3 = *(const float4*)(p + 12);
    union { short s[16]; int4 v[2]; } u;
    u.s[0] = (short)f2bf(v0.x);  u.s[1] = (short)f2bf(v0.y);
    u.s[2] = (short)f2bf(v0.z);  u.s[3] = (short)f2bf(v0.w);
    u.s[4] = (short)f2bf(v1.x);  u.s[5] = (short)f2bf(v1.y);
    u.s[6] = (short)f2bf(v1.z);  u.s[7] = (short)f2bf(v1.w);
    u.s[8] = (short)f2bf(v2.x);  u.s[9] = (short)f2bf(v2.y);
    u.s[10] = (short)f2bf(v2.z); u.s[11] = (short)f2bf(v2.w);
    u.s[12] = (short)f2bf(v3.x); u.s[13] = (short)f2bf(v3.y);
    u.s[14] = (short)f2bf(v3.z); u.s[15] = (short)f2bf(v3.w);
    int4* lp = (int4*)(L + row * 40 + half * 16);
    lp[0] = u.v[0];
    lp[1] = u.v[1];
  }
  __syncthreads();
  short* out = dst + (((size_t)(mt * 64 + kt)) << 12);
#pragma unroll
  for (int i = 0; i < 2; i++) {
    int ch = i * 256 + tid;
    int cc = ch & 15, qq = (ch >> 4) & 3, rt = ch >> 6;
    int4 v = *(const int4*)(L + (rt * 16 + cc) * 40 + qq * 8);
    *(int4*)(out + ch * 8) = v;
  }
}

// ---------------- QKV GEMM + bias + RoPE + fragment-order scatter ----------
__global__ __launch_bounds__(256) void qkv_gemm(
    const short* __restrict__ Xt, const short* __restrict__ Wt,
    const float* __restrict__ bq, const float2* __restrict__ rope,
    short* __restrict__ Qg, short* __restrict__ Kg, short* __restrict__ Vg) {
  __shared__ __align__(16) short As[4096];
  __shared__ __align__(16) short Bs[4096];

  const int tid = threadIdx.x;
  const int w = tid >> 6, lane = tid & 63;
  const int q = lane >> 4, c = lane & 15;
  const int wy = w >> 1, wx = w & 1;
  const int bn = blockIdx.x, bm = blockIdx.y;

  const short* Abase = Xt + (size_t)bm * 64 * 4096;
  const short* Bbase = Wt + (size_t)bn * 64 * 4096;

  f32x4 acc[4][4];
#pragma unroll
  for (int i = 0; i < 4; i++)
#pragma unroll
    for (int jl = 0; jl < 4; jl++) acc[i][jl] = (f32x4){0.f, 0.f, 0.f, 0.f};

  for (int kt = 0; kt < 64; kt++) {
    const short* Ak = Abase + (size_t)kt * 4096;
    const short* Bk = Bbase + (size_t)kt * 4096;
#pragma unroll
    for (int i = 0; i < 2; i++) {
      int ch = i * 256 + tid;
      gl_lds16(Ak + ch * 8, As + ch * 8);
      gl_lds16(Bk + ch * 8, Bs + ch * 8);
    }
    __syncthreads();
    bf16x8 a[4], b[4];
#pragma unroll
    for (int i = 0; i < 4; i++)
      a[i] = *(const bf16x8*)(As + (wy * 4 + i) * 512 + lane * 8);
#pragma unroll
    for (int jl = 0; jl < 4; jl++) {
      int ct = 2 * wx + (jl & 1) + ((jl >> 1) << 2);
      b[jl] = *(const bf16x8*)(Bs + ct * 512 + lane * 8);
    }
#pragma unroll
    for (int i = 0; i < 4; i++)
#pragma unroll
      for (int jl = 0; jl < 4; jl++)
        acc[i][jl] = __builtin_amdgcn_mfma_f32_16x16x32_bf16(a[i], b[jl], acc[i][jl], 0, 0, 0);
    __syncthreads();
  }

  const int head = bn / 3, typ = bn - head * 3;
  const int b = bm >> 3;
  const int bh = b * H_ + head;
  const int s0 = (bm & 7) << 7;

  int ctl[4];
  float bias[4];
#pragma unroll
  for (int jl = 0; jl < 4; jl++) {
    ctl[jl] = 2 * wx + (jl & 1) + ((jl >> 1) << 2);
    bias[jl] = bq[bn * 128 + ctl[jl] * 16 + c];
  }
#pragma unroll
  for (int i = 0; i < 4; i++)
#pragma unroll
    for (int jl = 0; jl < 4; jl++)
#pragma unroll
      for (int r = 0; r < 4; r++) acc[i][jl][r] += bias[jl];

  if (typ < 2) {
#pragma unroll
    for (int i = 0; i < 4; i++)
#pragma unroll
      for (int r = 0; r < 4; r++) {
        int s = s0 + wy * 64 + i * 16 + q * 4 + r;
#pragma unroll
        for (int jl = 0; jl < 2; jl++) {
          float2 cs = rope[s * 64 + ctl[jl] * 16 + c];
          float x1 = acc[i][jl][r], x2 = acc[i][jl + 2][r];
          acc[i][jl][r] = x1 * cs.x - x2 * cs.y;
          acc[i][jl + 2][r] = x2 * cs.x + x1 * cs.y;
        }
      }
    if (typ == 0) {
      short* dst = Qg + (size_t)bh * S_ * HD;
#pragma unroll
      for (int i = 0; i < 4; i++)
#pragma unroll
        for (int r = 0; r < 4; r++) {
          int s = s0 + wy * 64 + i * 16 + q * 4 + r;
          short* row = dst + (size_t)s * HD;
#pragma unroll
          for (int jl = 0; jl < 4; jl++)
            row[ctl[jl] * 16 + c] = (short)f2bf(acc[i][jl][r] * 0.08838834764831845f);
        }
    } else {
      short* dst = Kg + (size_t)bh * 16 * 8192 + (size_t)((s0 >> 6) + wy) * 8192;
#pragma unroll
      for (int i = 0; i < 4; i++)
#pragma unroll
        for (int jl = 0; jl < 4; jl++) {
          int ks = ctl[jl] >> 1;
          int qqf = ((ctl[jl] & 1) << 1) + (c >> 3);
          short* p = dst + (ks * 4 + i) * 512 + qqf * 128 + (c & 7);
#pragma unroll
          for (int r = 0; r < 4; r++)
            p[(q * 4 + r) * 8] = (short)f2bf(acc[i][jl][r]);
        }
    }
  } else {
    short* dst = Vg + (size_t)bh * 16 * 8192 + (size_t)((s0 >> 6) + wy) * 8192;
#pragma unroll
    for (int i = 0; i < 4; i++)
#pragma unroll
      for (int jl = 0; jl < 4; jl++)
#pragma unroll
        for (int r = 0; r < 4; r++) {
          int sl = q * 4 + r;
          int qqf = ((i & 1) << 1) + (sl >> 3);
          dst[((i >> 1) * 8 + ctl[jl]) * 512 + qqf * 128 + c * 8 + (sl & 7)] =
              (short)f2bf(acc[i][jl][r]);
        }
  }
}

// ---------------- causal flash attention ----------------
// 512-thread blocks, q-tile 128 (8 waves x 16 q-rows), KT=64.
// Paired q-tiles (p, 7-p): every block does exactly 18 tile-iterations.
// K double-buffered; manual s_waitcnt vmcnt(N) + raw s_barrier pipelining.
__global__ __launch_bounds__(512) void flash_attn(
    const short* __restrict__ Qg, const short* __restrict__ Kg,
    const short* __restrict__ Vg, float* __restrict__ out) {
  __shared__ __align__(16) short Kb[2][8192];  // 32 KB
  __shared__ __align__(16) short Vb[8192];     // 16 KB
  __shared__ __align__(16) short Ps[8192];     // 16 KB, wave-private 2 KB regions

  const int tid = threadIdx.x;
  const int w = tid >> 6, lane = tid & 63;
  const int q = lane >> 4, c = lane & 15;
  const int bh = blockIdx.x, pp = blockIdx.y;  // XCD = bh%8 -> balanced
  const int b = bh >> 4, h = bh & 15;

  const short* Qh = Qg + (size_t)bh * S_ * HD;
  const short* Kh = Kg + (size_t)bh * 16 * 8192;
  const short* Vh = Vg + (size_t)bh * 16 * 8192;

#pragma unroll
  for (int ph = 0; ph < 2; ph++) {
    const int qt = ph ? 7 - pp : pp;
    const int q0 = qt * 128;
    const int n = 2 * qt + 2;  // 64-wide k-tiles covering k < q0+128

    bf16x8 aq[4];  // wave w owns q-rows q0 + w*16 + [0,16)
#pragma unroll
    for (int ks = 0; ks < 4; ks++)
      aq[ks] = *(const bf16x8*)(Qh + (size_t)(q0 + w * 16 + c) * HD + ks * 32 + q * 8);

    f32x4 o[8];
    float m_[4], l_[4];
#pragma unroll
    for (int tj = 0; tj < 8; tj++) o[tj] = (f32x4){0.f, 0.f, 0.f, 0.f};
#pragma unroll
    for (int r = 0; r < 4; r++) { m_[r] = -1e30f; l_[r] = 0.f; }

    // pre-stage K0 (2 instr/thread) then V0 (2 instr/thread)
#pragma unroll
    for (int i = 0; i < 2; i++) {
      int ch = i * 512 + tid;
      gl_lds16(Kh + ch * 8, &Kb[0][ch * 8]);
    }
#pragma unroll
    for (int i = 0; i < 2; i++) {
      int ch = i * 512 + tid;
      gl_lds16(Vh + ch * 8, Vb + ch * 8);
    }

    for (int it = 0; it < n; it++) {
      const int cur = it & 1;
      // wait K(it); newest 2 (V(it)) stay in flight
      asm volatile("s_waitcnt vmcnt(2)" ::: "memory");
      __builtin_amdgcn_s_barrier();  // B1: K(it) visible

      f32x4 s[4];
#pragma unroll
      for (int tj = 0; tj < 4; tj++) s[tj] = (f32x4){0.f, 0.f, 0.f, 0.f};
#pragma unroll
      for (int ks = 0; ks < 4; ks++)
#pragma unroll
        for (int tj = 0; tj < 4; tj++) {
          bf16x8 bk = *(const bf16x8*)(&Kb[cur][(ks * 4 + tj) * 512 + lane * 8]);
          s[tj] = __builtin_amdgcn_mfma_f32_16x16x32_bf16(aq[ks], bk, s[tj], 0, 0, 0);
        }

      // prefetch K(it+1); last reader of Kb[cur^1] finished before B2(it-1)
      if (it + 1 < n) {
#pragma unroll
        for (int i = 0; i < 2; i++) {
          int ch = i * 512 + tid;
          gl_lds16(Kh + (size_t)(it + 1) * 8192 + ch * 8, &Kb[cur ^ 1][ch * 8]);
        }
      }

      if (it >= 2 * qt) {  // diagonal-overlapping tiles: causal mask
#pragma unroll
        for (int tj = 0; tj < 4; tj++) {
          int kg = it * 64 + tj * 16 + c;
#pragma unroll
          for (int r = 0; r < 4; r++) {
            int qg = q0 + w * 16 + q * 4 + r;
            if (kg > qg) s[tj][r] = -1e30f;
          }
        }
      }

      // online softmax (DPP reductions within the 16-lane col group)
#pragma unroll
      for (int r = 0; r < 4; r++) {
        float mx = fmaxf(fmaxf(s[0][r], s[1][r]), fmaxf(s[2][r], s[3][r]));
        mx = red_max16(mx);
        float mn = fmaxf(m_[r], mx);
        float alpha = __expf(m_[r] - mn);
        m_[r] = mn;
        float rs = 0.f;
#pragma unroll
        for (int tj = 0; tj < 4; tj++) {
          float e = __expf(s[tj][r] - mn);
          s[tj][r] = e;
          rs += e;
        }
        rs = red_sum16(rs);
        l_[r] = l_[r] * alpha + rs;
#pragma unroll
        for (int tjd = 0; tjd < 8; tjd++) o[tjd][r] *= alpha;
      }

      // wait V(it): only K(it+1) prefetch (2, newer) may remain
      if (it + 1 < n)
        asm volatile("s_waitcnt vmcnt(2)" ::: "memory");
      else
        asm volatile("s_waitcnt vmcnt(0)" ::: "memory");
      __builtin_amdgcn_s_barrier();  // B2: V(it) visible

      // P: C-layout -> wave-private A-layout region (2 KB per wave)
#pragma unroll
      for (int tj = 0; tj < 4; tj++) {
        int base = w * 1024 + (tj >> 1) * 512 + (((tj & 1) << 1) + (c >> 3)) * 128 + (c & 7);
#pragma unroll
        for (int r = 0; r < 4; r++)
          Ps[base + (q * 4 + r) * 8] = (short)f2bf(s[tj][r]);
      }

#pragma unroll
      for (int ks2 = 0; ks2 < 2; ks2++) {
        bf16x8 ap = *(const bf16x8*)(Ps + w * 1024 + ks2 * 512 + lane * 8);
#pragma unroll
        for (int tjd = 0; tjd < 8; tjd++) {
          bf16x8 bv = *(const bf16x8*)(Vb + (ks2 * 8 + tjd) * 512 + lane * 8);
          o[tjd] = __builtin_amdgcn_mfma_f32_16x16x32_bf16(ap, bv, o[tjd], 0, 0, 0);
        }
      }
      __builtin_amdgcn_s_barrier();  // B3: all waves done reading Vb

      // stage V(it+1); drains at B2(it+1), overlapped by QK+softmax
      if (it + 1 < n) {
#pragma unroll
        for (int i = 0; i < 2; i++) {
          int ch = i * 512 + tid;
          gl_lds16(Vh + (size_t)(it + 1) * 8192 + ch * 8, Vb + ch * 8);
        }
      }
    }

#pragma unroll
    for (int r = 0; r < 4; r++) {
      float inv = 1.0f / l_[r];
      int sg = q0 + w * 16 + q * 4 + r;
      float* dst = out + (size_t)(b * S_ + sg) * D_ + h * HD;
#pragma unroll
      for (int tjd = 0; tjd < 8; tjd++) dst[tjd * 16 + c] = o[tjd][r] * inv;
    }
    // phase ends with zero outstanding staging loads (last iter stages nothing);
    // phase-1 B1's vmcnt(2) also drains these output stores (correct, cheap).
  }
}

extern "C" void kernel_launch(void* const* d_in, const int* in_sizes, int n_in,
                              void* d_out, int out_size, void* d_ws, size_t ws_size,
                              hipStream_t stream) {
  (void)in_sizes; (void)n_in; (void)out_size; (void)ws_size;
  const float* hs = (const float*)d_in[0];
  const float* wq = (const float*)d_in[1];
  const float* bq = (const float*)d_in[2];
  char* ws = (char*)d_ws;
  short* Xt = (short*)(ws);
  short* Wt = (short*)(ws + 16777216);
  short* Qg = (short*)(ws + 41943040);
  short* Kg = (short*)(ws + 58720256);
  short* Vg = (short*)(ws + 75497472);
  float2* tbl = (float2*)(ws + 92274688);

  hipLaunchKernelGGL(prep, dim3(5376), dim3(256), 0, stream, hs, Xt, wq, Wt, tbl);
  hipLaunchKernelGGL(qkv_gemm, dim3(48, 32), dim3(256), 0, stream, Xt, Wt, bq, tbl, Qg, Kg, Vg);
  hipLaunchKernelGGL(flash_attn, dim3(64, 4), dim3(512), 0, stream, Qg, Kg, Vg, (float*)d_out);
}